// Round 8
// baseline (373.266 us; speedup 1.0000x reference)
//
#include <hip/hip_runtime.h>
#include <hip/hip_cooperative_groups.h>

namespace cg = cooperative_groups;

__device__ inline float wsum(float v) {
#pragma unroll
  for (int off = 32; off; off >>= 1) v += __shfl_xor(v, off, 64);
  return v;
}

struct MegaParams {
  const float *query, *entity, *conv_w, *conv_b, *q_w, *q_b, *k_w, *k_b;
  const float *v_w, *v_b, *e_w, *e_b, *attn_w, *attn_b, *deconv_w, *deconv_b;
  const float *out_w, *out_b;
  float *nq, *e_buf, *v_buf, *qw_red, *kw_red, *qb_red, *kb_red;
  float *Abuf, *Bkbuf, *Ewbuf, *a_buf, *y0, *y1, *dout;
};

// =============== conv-like GEMM core (direct interleaved weights) ===============
// C[m,n] = bias[n] + sum_i ( a_cur[m,i]*Wc[n,i] + a_prev[m-2,i]*Wp[n,i] ),
// i in [kbase, kbase+kcount). bias may be nullptr (partial).
// TAPMODE 0 (conv):   W (n,i,tap) row-major interleaved; cur=tap1, prev=tap0.
// TAPMODE 1 (deconv): W (i,n,tap) k-major interleaved;   cur=tap0, prev=tap1.
template <int TAPMODE>
__device__ __forceinline__ void conv_core(const float* __restrict__ A,
                                          const float* __restrict__ W,
                                          const float* __restrict__ bias,
                                          float* __restrict__ C,
                                          int m0, int n0, int kbase, int kcount,
                                          float* smem) {
  float* As  = smem;           // [32 k][36] rows 0..33 = global m0-2..m0+31
  float* Bs0 = smem + 1152;    // [32 i][68] tap0
  float* Bs1 = Bs0 + 2176;     // [32 i][68] tap1
  const int tid = threadIdx.x;
  const int ar = tid >> 3, ak4 = (tid & 7) << 2;
  const int gmA = m0 - 2 + ar;
  const bool extra = (tid < 16);
  const int ar2 = 32 + (tid >> 3);
  const int gmA2 = m0 + 30 + (tid >> 3);
  const int tn = tid & 15, tm = tid >> 4;
  const int bn = tid >> 2, ig = tid & 3;  // TAPMODE 0
  const int il = tid >> 3, ng = tid & 7;  // TAPMODE 1

  float4 pa, pa2, pb[4];
  auto ld = [&](int kt) {
    int gi = kbase + kt;
    pa = (gmA >= 0) ? *(const float4*)(A + (size_t)gmA * 768 + gi + ak4)
                    : make_float4(0.f, 0.f, 0.f, 0.f);
    if (extra) pa2 = *(const float4*)(A + (size_t)gmA2 * 768 + gi + ak4);
    if (TAPMODE == 0) {
      const float* wrow = W + (size_t)(n0 + bn) * 1536 + 2 * (gi + ig * 8);
#pragma unroll
      for (int c = 0; c < 4; ++c) pb[c] = *(const float4*)(wrow + 4 * c);
    } else {
      const float* wrow = W + (size_t)(gi + il) * 1536 + 2 * (n0 + ng * 8);
#pragma unroll
      for (int c = 0; c < 4; ++c) pb[c] = *(const float4*)(wrow + 4 * c);
    }
  };

  ld(0);
  float acc[2][4] = {};
  for (int kt = 0; kt < kcount; kt += 32) {
#pragma unroll
    for (int c = 0; c < 4; ++c) {
      float v = (c == 0) ? pa.x : (c == 1) ? pa.y : (c == 2) ? pa.z : pa.w;
      As[(ak4 + c) * 36 + ar] = v;
    }
    if (extra) {
#pragma unroll
      for (int c = 0; c < 4; ++c) {
        float v = (c == 0) ? pa2.x : (c == 1) ? pa2.y : (c == 2) ? pa2.z : pa2.w;
        As[(ak4 + c) * 36 + ar2] = v;
      }
    }
    if (TAPMODE == 0) {
#pragma unroll
      for (int c = 0; c < 4; ++c) {
        int i_l = ig * 8 + 2 * c;
        Bs0[i_l * 68 + bn] = pb[c].x; Bs1[i_l * 68 + bn] = pb[c].y;
        Bs0[(i_l + 1) * 68 + bn] = pb[c].z; Bs1[(i_l + 1) * 68 + bn] = pb[c].w;
      }
    } else {
#pragma unroll
      for (int c = 0; c < 4; ++c) {
        int n_l = ng * 8 + 2 * c;
        Bs0[il * 68 + n_l] = pb[c].x; Bs1[il * 68 + n_l] = pb[c].y;
        Bs0[il * 68 + n_l + 1] = pb[c].z; Bs1[il * 68 + n_l + 1] = pb[c].w;
      }
    }
    __syncthreads();
    if (kt + 32 < kcount) ld(kt + 32);
#pragma unroll
    for (int i = 0; i < 32; ++i) {
      float4 b0 = *(const float4*)(Bs0 + i * 68 + (tn << 2));
      float4 b1 = *(const float4*)(Bs1 + i * 68 + (tn << 2));
      float ap0 = As[i * 36 + (tm << 1)];
      float ap1 = As[i * 36 + (tm << 1) + 1];
      float ac0 = As[i * 36 + (tm << 1) + 2];
      float ac1 = As[i * 36 + (tm << 1) + 3];
      float bc[4] = {b0.x, b0.y, b0.z, b0.w};
      float bp[4] = {b1.x, b1.y, b1.z, b1.w};
#pragma unroll
      for (int jj = 0; jj < 4; ++jj) {
        if (TAPMODE == 0) {
          acc[0][jj] += ac0 * bp[jj] + ap0 * bc[jj];
          acc[1][jj] += ac1 * bp[jj] + ap1 * bc[jj];
        } else {
          acc[0][jj] += ac0 * bc[jj] + ap0 * bp[jj];
          acc[1][jj] += ac1 * bc[jj] + ap1 * bp[jj];
        }
      }
    }
    __syncthreads();
  }
#pragma unroll
  for (int j = 0; j < 2; ++j) {
    int m = m0 + (tm << 1) + j;
    float b0 = bias ? bias[n0 + (tn << 2) + 0] : 0.f;
    float b1 = bias ? bias[n0 + (tn << 2) + 1] : 0.f;
    float b2 = bias ? bias[n0 + (tn << 2) + 2] : 0.f;
    float b3 = bias ? bias[n0 + (tn << 2) + 3] : 0.f;
    float4 o = make_float4(acc[j][0] + b0, acc[j][1] + b1,
                           acc[j][2] + b2, acc[j][3] + b3);
    *(float4*)(C + (size_t)m * 768 + n0 + (tn << 2)) = o;
  }
}

// =============== plain GEMM core: C[256,N] = Aeff[256,768] * Bw[N,768]^T + bias ====
// SUM2: Aeff = A + A2 + ab (row-broadcast).
template <bool SUM2>
__device__ __forceinline__ void gemm_plain(const float* __restrict__ A,
                                           const float* __restrict__ A2,
                                           const float* __restrict__ ab,
                                           const float* __restrict__ Bw,
                                           const float* __restrict__ bias,
                                           float* __restrict__ C, int N,
                                           int m0, int n0, float* smem) {
  float* As = smem;          // [32][36]
  float* Bs = smem + 1152;   // [32][68]
  const int tid = threadIdx.x;
  const int ar = tid >> 3, ak4 = (tid & 7) << 2;
  const int br = tid >> 2, bk4 = (tid & 3) << 2;
  const int tn = tid & 15, tm = tid >> 4;
  const float* Arow = A + (size_t)(m0 + ar) * 768;
  const float* A2row = SUM2 ? A2 + (size_t)(m0 + ar) * 768 : nullptr;
  const float* Brow = Bw + (size_t)(n0 + br) * 768;
  float4 pa, pb0, pb1;
  auto ld = [&](int gi) {
    pa = *(const float4*)(Arow + gi + ak4);
    if (SUM2) {
      float4 t2 = *(const float4*)(A2row + gi + ak4);
      float4 t3 = *(const float4*)(ab + gi + ak4);
      pa.x += t2.x + t3.x; pa.y += t2.y + t3.y;
      pa.z += t2.z + t3.z; pa.w += t2.w + t3.w;
    }
    pb0 = *(const float4*)(Brow + gi + bk4);
    pb1 = *(const float4*)(Brow + gi + bk4 + 16);
  };
  ld(0);
  float acc[2][4] = {};
  for (int kt = 0; kt < 768; kt += 32) {
    As[(ak4 + 0) * 36 + ar] = pa.x; As[(ak4 + 1) * 36 + ar] = pa.y;
    As[(ak4 + 2) * 36 + ar] = pa.z; As[(ak4 + 3) * 36 + ar] = pa.w;
    Bs[(bk4 + 0) * 68 + br] = pb0.x; Bs[(bk4 + 1) * 68 + br] = pb0.y;
    Bs[(bk4 + 2) * 68 + br] = pb0.z; Bs[(bk4 + 3) * 68 + br] = pb0.w;
    Bs[(bk4 + 16) * 68 + br] = pb1.x; Bs[(bk4 + 17) * 68 + br] = pb1.y;
    Bs[(bk4 + 18) * 68 + br] = pb1.z; Bs[(bk4 + 19) * 68 + br] = pb1.w;
    __syncthreads();
    if (kt + 32 < 768) ld(kt + 32);
#pragma unroll
    for (int k = 0; k < 32; ++k) {
      float2 a2 = *(const float2*)(As + k * 36 + (tm << 1));
      float4 b4 = *(const float4*)(Bs + k * 68 + (tn << 2));
      float aa[2] = {a2.x, a2.y};
      float bb[4] = {b4.x, b4.y, b4.z, b4.w};
#pragma unroll
      for (int i = 0; i < 2; ++i)
#pragma unroll
        for (int j = 0; j < 4; ++j) acc[i][j] += aa[i] * bb[j];
    }
    __syncthreads();
  }
#pragma unroll
  for (int i = 0; i < 2; ++i) {
    int m = m0 + (tm << 1) + i;
    const float* bp = bias + n0 + (tn << 2);
    float4 o = make_float4(acc[i][0] + bp[0], acc[i][1] + bp[1],
                           acc[i][2] + bp[2], acc[i][3] + bp[3]);
    *(float4*)(C + (size_t)m * N + n0 + (tn << 2)) = o;
  }
}

// =============== the single mega kernel (5 phases, grid-wide sync) ===============
__global__ __launch_bounds__(256) void mega_kernel(MegaParams p) {
  cg::grid_group grid = cg::this_grid();
  __shared__ float smem[5504];
  const int bid = blockIdx.x;
  const int tid = threadIdx.x;
  const int wv4 = tid >> 6, lane = tid & 63;

  // ---------------- Phase 1: conv | e-gemm | fold | Ew-dots ----------------
  if (bid < 96) {
    conv_core<0>(p.query, p.conv_w, p.conv_b, p.nq,
                 (bid / 12) * 32, (bid % 12) * 64, 0, 768, smem);
  } else if (bid < 144) {
    int t = bid - 96;
    gemm_plain<false>(p.entity, nullptr, nullptr, p.e_w, p.e_b, p.e_buf, 384,
                      (t / 6) * 32, (t % 6) * 64, smem);
  } else if (bid < 183) {
    int W = (bid - 144) * 4 + wv4;  // 0..155
    if (W < 72) {
      int h = W / 12, ib = W % 12, i = ib * 64 + lane;
      float s = 0.f;
#pragma unroll 8
      for (int d = 0; d < 64; ++d) s += p.q_w[(h * 64 + d) * 768 + i] * p.attn_w[d];
      p.qw_red[h * 768 + i] = s;
    } else if (W < 144) {
      int r = W - 72;
      int h = r / 12, ib = r % 12, i = ib * 64 + lane;
      float s = 0.f;
#pragma unroll 8
      for (int d = 0; d < 64; ++d) s += p.k_w[(h * 64 + d) * 768 + i] * p.attn_w[64 + d];
      p.kw_red[h * 768 + i] = s;
    } else if (W < 156) {
      int r = W - 144;
      if (r < 6) {
        float s = wsum(p.q_b[r * 64 + lane] * p.attn_w[lane]);
        if (lane == 0) p.qb_red[r] = s;
      } else {
        float s = wsum(p.k_b[(r - 6) * 64 + lane] * p.attn_w[64 + lane]);
        if (lane == 0) p.kb_red[r - 6] = s;
      }
    }
  } else if (bid < 247) {
    int row = (bid - 183) * 4 + wv4;  // 0..255 = t*2+b
    const float* erow = p.entity + (size_t)row * 768;
    float wvl = p.attn_w[128 + lane];
#pragma unroll
    for (int cb = 0; cb < 12; ++cb) {
      float s = wsum(erow[cb * 64 + lane] * wvl);
      if (lane == 0) p.Ewbuf[row * 12 + cb] = s;
    }
  }
  grid.sync();

  // ---------------- Phase 2: v-gemm | A-dots | Bk-dots ----------------
  if (bid < 48) {
    gemm_plain<false>(p.nq, nullptr, nullptr, p.v_w, p.v_b, p.v_buf, 384,
                      (bid / 6) * 32, (bid % 6) * 64, smem);
  } else {
    int wid = (bid - 48) * 4 + wv4;  // 0..831
    for (int W = wid; W < 6144; W += 832) {
      if (W < 1536) {  // A q-part
        int x = W & 127, q = W >> 7;
        int b = q / 6, h = q % 6;
        const size_t row = (size_t)(x * 2 + b) * 768;
        const float* ww = p.qw_red + h * 768;
        float pacc = 0.f;
#pragma unroll
        for (int it = 0; it < 12; ++it) {
          int i = it * 64 + lane;
          pacc += p.nq[row + i] * ww[i];
        }
        float s = wsum(pacc) + p.qb_red[h];
        if (lane == 0) p.Abuf[(b * 12 + h) * 128 + x] = s;
      } else if (W < 3072) {  // A e-part
        int r = W - 1536;
        int x = r & 127, q = r >> 7;
        int b = q / 6, he = q % 6;
        float s = wsum(p.e_buf[(size_t)(x * 2 + b) * 384 + he * 64 + lane] * p.attn_w[lane]);
        if (lane == 0) p.Abuf[(b * 12 + 6 + he) * 128 + x] = s;
      } else if (W < 4608) {  // Bk q-part
        int r = W - 3072;
        int l = r & 127, q = r >> 7;
        int b = q / 6, h = q % 6;
        const size_t row = (size_t)(l * 2 + b) * 768;
        const float* ww = p.kw_red + h * 768;
        float pacc = 0.f;
#pragma unroll
        for (int it = 0; it < 12; ++it) {
          int i = it * 64 + lane;
          pacc += p.nq[row + i] * ww[i];
        }
        float s = wsum(pacc) + p.kb_red[h];
        if (lane == 0) p.Bkbuf[(b * 12 + h) * 128 + l] = s;
      } else {  // Bk e-part
        int r = W - 4608;
        int l = r & 127, q = r >> 7;
        int b = q / 6, he = q % 6;
        float s = wsum(p.e_buf[(size_t)(l * 2 + b) * 384 + he * 64 + lane] * p.attn_w[64 + lane]);
        if (lane == 0) p.Bkbuf[(b * 12 + 6 + he) * 128 + l] = s;
      }
    }
  }
  grid.sync();

  // ---------------- Phase 3: scores + leaky_relu + softmax + PV ----------------
  {
    float* ps   = smem;            // [2][128]
    float* redm = smem + 256;      // [2][2]
    float* reds = smem + 260;      // [2][2]
    float* pv   = smem + 264;      // [2][2][64]
    const int half = tid >> 7;
    const int t = tid & 127;
    const int widx = (tid >> 6) & 1;
    const float ab0 = p.attn_b[0];
    for (int r = 0; r < 6; ++r) {
      int u = bid * 12 + 2 * r + half;      // (bh,i2) unit
      int bh = u >> 7, i2 = u & 127;
      int j = t;
      int G = u * 128 + j;
      int mq = G % 24, xq = (G / 24) >> 7;
      int mk = u % 24;
      int cb = G % 12, gb = G / 12;
      int be = gb & 1, ij = gb >> 1, ie = ij >> 7, je = ij & 127;
      float s = p.Abuf[mq * 128 + xq] + p.Bkbuf[mk * 128 + j] +
                p.Ewbuf[ie * 24 + be * 12 + cb] - p.Ewbuf[je * 24 + be * 12 + cb] + ab0;
      s = s >= 0.f ? s : 0.01f * s;

      float mv = s;
#pragma unroll
      for (int off = 32; off; off >>= 1) mv = fmaxf(mv, __shfl_xor(mv, off, 64));
      if (lane == 0) redm[half * 2 + widx] = mv;
      __syncthreads();
      float gmax = fmaxf(redm[half * 2], redm[half * 2 + 1]);
      float ex = expf(s - gmax);
      float sv = wsum(ex);
      if (lane == 0) reds[half * 2 + widx] = sv;
      __syncthreads();
      float gsum = reds[half * 2] + reds[half * 2 + 1];
      ps[half * 128 + t] = ex / gsum;
      __syncthreads();

      int d = t & 63, jh = t >> 6;
      int b = bh / 12, h = bh % 12;
      const float* src = (h < 6) ? (p.v_buf + h * 64) : (p.e_buf + (h - 6) * 64);
      float acc = 0.f;
#pragma unroll 8
      for (int jj = 0; jj < 64; ++jj) {
        int jx = jh * 64 + jj;
        acc += ps[half * 128 + jx] * src[(size_t)(jx * 2 + b) * 384 + d];
      }
      pv[half * 128 + jh * 64 + d] = acc;
      __syncthreads();
      if (t < 64) {
        p.a_buf[(size_t)(i2 * 2 + b) * 768 + h * 64 + t] =
            pv[half * 128 + t] + pv[half * 128 + 64 + t];
      }
      __syncthreads();
    }
  }
  grid.sync();

  // ---------------- Phase 4: deconv split-K2 -> y0/y1 partials ----------------
  if (bid < 192) {
    int kz = bid / 96, t = bid % 96;
    conv_core<1>(p.a_buf, p.deconv_w, nullptr, kz ? p.y1 : p.y0,
                 (t / 12) * 32, (t % 12) * 64, kz * 384, 384, smem);
  }
  grid.sync();

  // ---------------- Phase 5: out = (y0+y1+deconv_b) @ out_w^T + out_b ----------------
  if (bid < 96) {
    gemm_plain<true>(p.y0, p.y1, p.deconv_b, p.out_w, p.out_b, p.dout, 768,
                     (bid / 12) * 32, (bid % 12) * 64, smem);
  }
}

extern "C" void kernel_launch(void* const* d_in, const int* in_sizes, int n_in,
                              void* d_out, int out_size, void* d_ws, size_t ws_size,
                              hipStream_t stream) {
  MegaParams p;
  p.query    = (const float*)d_in[0];
  p.entity   = (const float*)d_in[1];
  p.conv_w   = (const float*)d_in[2];
  p.conv_b   = (const float*)d_in[3];
  p.q_w      = (const float*)d_in[4];
  p.q_b      = (const float*)d_in[5];
  p.k_w      = (const float*)d_in[6];
  p.k_b      = (const float*)d_in[7];
  p.v_w      = (const float*)d_in[8];
  p.v_b      = (const float*)d_in[9];
  p.e_w      = (const float*)d_in[10];
  p.e_b      = (const float*)d_in[11];
  p.attn_w   = (const float*)d_in[12];
  p.attn_b   = (const float*)d_in[13];
  p.deconv_w = (const float*)d_in[14];
  p.deconv_b = (const float*)d_in[15];
  p.out_w    = (const float*)d_in[16];
  p.out_b    = (const float*)d_in[17];

  float* ws  = (float*)d_ws;
  p.nq     = ws;                  // 196608
  p.e_buf  = p.nq + 196608;       // 98304
  p.v_buf  = p.e_buf + 98304;     // 98304
  p.qw_red = p.v_buf + 98304;     // 4608
  p.kw_red = p.qw_red + 4608;     // 4608
  p.qb_red = p.kw_red + 4608;     // 8
  p.kb_red = p.qb_red + 8;        // 8
  p.Abuf   = p.kb_red + 8;        // 3072
  p.Bkbuf  = p.Abuf + 3072;       // 3072
  p.Ewbuf  = p.Bkbuf + 3072;      // 3072
  p.a_buf  = p.Ewbuf + 3072;      // 196608
  p.y0     = p.a_buf + 196608;    // 196608
  p.y1     = p.y0 + 196608;       // 196608
  p.dout   = (float*)d_out;

  void* args[] = {&p};
  hipLaunchCooperativeKernel((const void*)mega_kernel, dim3(256), dim3(256),
                             args, 0, stream);
}

// Round 9
// 184.791 us; speedup vs baseline: 2.0199x; 2.0199x over previous
//
#include <hip/hip_runtime.h>

#define ASS 34   // padded LDS stride for A tiles (2-way bank aliasing = free)
#define BSS 68   // padded LDS stride for B tiles (float4-aligned, 2-way)

__device__ inline float wsum(float v) {
#pragma unroll
  for (int off = 32; off; off >>= 1) v += __shfl_xor(v, off, 64);
  return v;
}

struct P {
  const float *query, *entity, *conv_w, *conv_b, *q_w, *q_b, *k_w, *k_b;
  const float *v_w, *v_b, *e_w, *e_b, *attn_w, *attn_b, *deconv_w, *deconv_b;
  const float *out_w, *out_b;
  float *nq0, *nq1, *nq2, *nq3, *e_buf, *v_buf, *qw_red, *kw_red, *qb_red, *kb_red;
  float *Abuf, *Bkbuf, *Ewbuf, *a_buf, *y, *dout;
};

// ======== conv-like GEMM (direct interleaved weights), double-buffered ========
// acc[m,n] = sum over pair-k in [kbase, kbase+32*ktiles) of
//            a_cur[m,i]*Wc[n,i] + a_prev[m-2,i]*Wp[n,i]
// TAPMODE 0 (conv):   W (n,i,tap); cur=tap1, prev=tap0.   out: direct partial
// TAPMODE 1 (deconv): W (i,n,tap); cur=tap0, prev=tap1.   out: atomic into pre-biased C
template <int TAPMODE, bool ATOMIC>
__device__ __forceinline__ void conv_v2(const float* __restrict__ A,
                                        const float* __restrict__ W,
                                        float* __restrict__ C,
                                        int m0, int n0, int kbase, int ktiles,
                                        float* smem) {
  float* AsB  = smem;                  // 2 x [32][ASS]
  float* Bs0B = smem + 2 * 32 * ASS;   // 2 x [32][BSS] tap0
  float* Bs1B = Bs0B + 2 * 32 * BSS;   // 2 x [32][BSS] tap1
  const int tid = threadIdx.x;
  const int ar = tid >> 3, ak4 = (tid & 7) << 2;
  const int gmA = m0 - 2 + ar;
  const bool extra = (tid < 16);
  const int ar2 = 32 + (tid >> 3);
  const int gmA2 = m0 + 30 + (tid >> 3);
  const int tn = tid & 15, tm = tid >> 4;
  const int bn = tid >> 2, ig = tid & 3;  // TAPMODE 0
  const int il = tid >> 3, ng = tid & 7;  // TAPMODE 1

  float4 pa, pa2, pb[4];
  auto ld = [&](int t) {
    int gi = kbase + t * 32;
    pa = (gmA >= 0) ? *(const float4*)(A + (size_t)gmA * 768 + gi + ak4)
                    : make_float4(0.f, 0.f, 0.f, 0.f);
    if (extra) pa2 = *(const float4*)(A + (size_t)gmA2 * 768 + gi + ak4);
    if (TAPMODE == 0) {
      const float* wrow = W + (size_t)(n0 + bn) * 1536 + 2 * (gi + ig * 8);
#pragma unroll
      for (int c = 0; c < 4; ++c) pb[c] = *(const float4*)(wrow + 4 * c);
    } else {
      const float* wrow = W + (size_t)(gi + il) * 1536 + 2 * (n0 + ng * 8);
#pragma unroll
      for (int c = 0; c < 4; ++c) pb[c] = *(const float4*)(wrow + 4 * c);
    }
  };

  ld(0);
  float acc[2][4] = {};
  for (int t = 0; t < ktiles; ++t) {
    float* As  = AsB + (t & 1) * (32 * ASS);
    float* Bs0 = Bs0B + (t & 1) * (32 * BSS);
    float* Bs1 = Bs1B + (t & 1) * (32 * BSS);
#pragma unroll
    for (int c = 0; c < 4; ++c) {
      float v = (c == 0) ? pa.x : (c == 1) ? pa.y : (c == 2) ? pa.z : pa.w;
      As[(ak4 + c) * ASS + ar] = v;
    }
    if (extra) {
#pragma unroll
      for (int c = 0; c < 4; ++c) {
        float v = (c == 0) ? pa2.x : (c == 1) ? pa2.y : (c == 2) ? pa2.z : pa2.w;
        As[(ak4 + c) * ASS + ar2] = v;
      }
    }
    if (TAPMODE == 0) {
#pragma unroll
      for (int c = 0; c < 4; ++c) {
        int i_l = ig * 8 + 2 * c;
        Bs0[i_l * BSS + bn] = pb[c].x; Bs1[i_l * BSS + bn] = pb[c].y;
        Bs0[(i_l + 1) * BSS + bn] = pb[c].z; Bs1[(i_l + 1) * BSS + bn] = pb[c].w;
      }
    } else {
#pragma unroll
      for (int c = 0; c < 4; ++c) {
        int n_l = ng * 8 + 2 * c;
        Bs0[il * BSS + n_l] = pb[c].x; Bs1[il * BSS + n_l] = pb[c].y;
        Bs0[il * BSS + n_l + 1] = pb[c].z; Bs1[il * BSS + n_l + 1] = pb[c].w;
      }
    }
    __syncthreads();
    if (t + 1 < ktiles) ld(t + 1);
#pragma unroll
    for (int i = 0; i < 32; ++i) {
      float4 b0 = *(const float4*)(Bs0 + i * BSS + (tn << 2));
      float4 b1 = *(const float4*)(Bs1 + i * BSS + (tn << 2));
      float ap0 = As[i * ASS + (tm << 1)];
      float ap1 = As[i * ASS + (tm << 1) + 1];
      float ac0 = As[i * ASS + (tm << 1) + 2];
      float ac1 = As[i * ASS + (tm << 1) + 3];
      float bc[4] = {b0.x, b0.y, b0.z, b0.w};
      float bp[4] = {b1.x, b1.y, b1.z, b1.w};
#pragma unroll
      for (int jj = 0; jj < 4; ++jj) {
        if (TAPMODE == 0) {  // cur*tap1 + prev*tap0
          acc[0][jj] += ac0 * bp[jj] + ap0 * bc[jj];
          acc[1][jj] += ac1 * bp[jj] + ap1 * bc[jj];
        } else {             // cur*tap0 + prev*tap1
          acc[0][jj] += ac0 * bc[jj] + ap0 * bp[jj];
          acc[1][jj] += ac1 * bc[jj] + ap1 * bp[jj];
        }
      }
    }
    // no trailing sync: next iter stores to the other buffer; the next
    // __syncthreads separates this compute from the t+2 overwrite.
  }
#pragma unroll
  for (int j = 0; j < 2; ++j) {
    int m = m0 + (tm << 1) + j;
    if (ATOMIC) {
#pragma unroll
      for (int jj = 0; jj < 4; ++jj)
        unsafeAtomicAdd(&C[(size_t)m * 768 + n0 + (tn << 2) + jj], acc[j][jj]);
    } else {
      float4 o = make_float4(acc[j][0], acc[j][1], acc[j][2], acc[j][3]);
      *(float4*)(C + (size_t)m * 768 + n0 + (tn << 2)) = o;
    }
  }
}

// ======== plain GEMM, double-buffered: C[.,N] (+)= Aeff[.,chunk] * Bw[N,768]^T =====
// NSUM==4: Aeff = A0+A1+A2+A3 + arow (row-broadcast). ATOMIC: add into pre-biased C.
template <int NSUM, bool ATOMIC>
__device__ __forceinline__ void gemm_v2(const float* __restrict__ A0,
                                        const float* __restrict__ A1,
                                        const float* __restrict__ A2,
                                        const float* __restrict__ A3,
                                        const float* __restrict__ arow,
                                        const float* __restrict__ Bw,
                                        const float* __restrict__ bias,
                                        float* __restrict__ C, int N,
                                        int m0, int n0, int kbase, int ktiles,
                                        float* smem) {
  float* AsB = smem;                  // 2 x [32][ASS]
  float* BsB = smem + 2 * 32 * ASS;   // 2 x [32][BSS]
  const int tid = threadIdx.x;
  const int ar = tid >> 3, ak4 = (tid & 7) << 2;
  const int br = tid >> 2, bk4 = (tid & 3) << 2;
  const int tn = tid & 15, tm = tid >> 4;
  const float* Brow = Bw + (size_t)(n0 + br) * 768;
  float4 pa, pb0, pb1;
  auto ld = [&](int t) {
    int gi = kbase + t * 32;
    size_t ao = (size_t)(m0 + ar) * 768 + gi + ak4;
    pa = *(const float4*)(A0 + ao);
    if constexpr (NSUM == 4) {
      float4 t1 = *(const float4*)(A1 + ao);
      float4 t2 = *(const float4*)(A2 + ao);
      float4 t3 = *(const float4*)(A3 + ao);
      float4 t4 = *(const float4*)(arow + gi + ak4);
      pa.x += t1.x + t2.x + t3.x + t4.x;
      pa.y += t1.y + t2.y + t3.y + t4.y;
      pa.z += t1.z + t2.z + t3.z + t4.z;
      pa.w += t1.w + t2.w + t3.w + t4.w;
    }
    pb0 = *(const float4*)(Brow + gi + bk4);
    pb1 = *(const float4*)(Brow + gi + bk4 + 16);
  };
  ld(0);
  float acc[2][4] = {};
  for (int t = 0; t < ktiles; ++t) {
    float* As = AsB + (t & 1) * (32 * ASS);
    float* Bs = BsB + (t & 1) * (32 * BSS);
    As[(ak4 + 0) * ASS + ar] = pa.x; As[(ak4 + 1) * ASS + ar] = pa.y;
    As[(ak4 + 2) * ASS + ar] = pa.z; As[(ak4 + 3) * ASS + ar] = pa.w;
    Bs[(bk4 + 0) * BSS + br] = pb0.x; Bs[(bk4 + 1) * BSS + br] = pb0.y;
    Bs[(bk4 + 2) * BSS + br] = pb0.z; Bs[(bk4 + 3) * BSS + br] = pb0.w;
    Bs[(bk4 + 16) * BSS + br] = pb1.x; Bs[(bk4 + 17) * BSS + br] = pb1.y;
    Bs[(bk4 + 18) * BSS + br] = pb1.z; Bs[(bk4 + 19) * BSS + br] = pb1.w;
    __syncthreads();
    if (t + 1 < ktiles) ld(t + 1);
#pragma unroll
    for (int k = 0; k < 32; ++k) {
      float a0 = As[k * ASS + (tm << 1)];
      float a1 = As[k * ASS + (tm << 1) + 1];
      float4 b4 = *(const float4*)(Bs + k * BSS + (tn << 2));
      float bb[4] = {b4.x, b4.y, b4.z, b4.w};
#pragma unroll
      for (int jj = 0; jj < 4; ++jj) {
        acc[0][jj] += a0 * bb[jj];
        acc[1][jj] += a1 * bb[jj];
      }
    }
  }
#pragma unroll
  for (int i = 0; i < 2; ++i) {
    int m = m0 + (tm << 1) + i;
    if (ATOMIC) {
#pragma unroll
      for (int jj = 0; jj < 4; ++jj)
        unsafeAtomicAdd(&C[(size_t)m * N + n0 + (tn << 2) + jj], acc[i][jj]);
    } else {
      const float* bp = bias + n0 + (tn << 2);
      float4 o = make_float4(acc[i][0] + bp[0], acc[i][1] + bp[1],
                             acc[i][2] + bp[2], acc[i][3] + bp[3]);
      *(float4*)(C + (size_t)m * N + n0 + (tn << 2)) = o;
    }
  }
}

// ======== Stage 1: conv splitk4 | e-gemm | attn_w fold | Ew dots | bias inits ========
__global__ __launch_bounds__(256) void s1(P p) {
  __shared__ float smem[2 * 32 * ASS + 4 * 32 * BSS];  // 10880 floats
  const int bid = blockIdx.x, tid = threadIdx.x;
  const int wv4 = tid >> 6, lane = tid & 63;
  if (bid < 384) {  // conv partials nq0..nq3 (no bias)
    int kz = bid & 3, t = bid >> 2;
    float* dst = (kz == 0) ? p.nq0 : (kz == 1) ? p.nq1 : (kz == 2) ? p.nq2 : p.nq3;
    conv_v2<0, false>(p.query, p.conv_w, dst, (t / 12) * 32, (t % 12) * 64,
                      kz * 192, 6, smem);
  } else if (bid < 432) {  // e = entity @ e_w^T + e_b (full K)
    int t = bid - 384;
    gemm_v2<0, false>(p.entity, nullptr, nullptr, nullptr, nullptr, p.e_w, p.e_b,
                      p.e_buf, 384, (t / 6) * 32, (t % 6) * 64, 0, 24, smem);
  } else if (bid < 472) {  // fold attn_w into q_w/k_w
    int W = (bid - 432) * 4 + wv4;
    if (W < 72) {
      int h = W / 12, ib = W % 12, i = ib * 64 + lane;
      float s = 0.f;
#pragma unroll 8
      for (int d = 0; d < 64; ++d) s += p.q_w[(h * 64 + d) * 768 + i] * p.attn_w[d];
      p.qw_red[h * 768 + i] = s;
    } else if (W < 144) {
      int r = W - 72;
      int h = r / 12, ib = r % 12, i = ib * 64 + lane;
      float s = 0.f;
#pragma unroll 8
      for (int d = 0; d < 64; ++d) s += p.k_w[(h * 64 + d) * 768 + i] * p.attn_w[64 + d];
      p.kw_red[h * 768 + i] = s;
    } else if (W < 156) {
      int r = W - 144;
      if (r < 6) {
        float s = wsum(p.q_b[r * 64 + lane] * p.attn_w[lane]);
        if (lane == 0) p.qb_red[r] = s;
      } else {
        float s = wsum(p.k_b[(r - 6) * 64 + lane] * p.attn_w[64 + lane]);
        if (lane == 0) p.kb_red[r - 6] = s;
      }
    }
  } else if (bid < 536) {  // Ew[t,b,cb]
    int row = (bid - 472) * 4 + wv4;  // 0..255 = t*2+b
    const float* erow = p.entity + (size_t)row * 768;
    float wvl = p.attn_w[128 + lane];
#pragma unroll
    for (int cb = 0; cb < 12; ++cb) {
      float s = wsum(erow[cb * 64 + lane] * wvl);
      if (lane == 0) p.Ewbuf[row * 12 + cb] = s;
    }
  } else {  // bias inits: v_buf=v_b, y=deconv_b, dout=out_b (float4 grid-stride)
    int iv = (bid - 536) * 256 + tid;  // 0..7679
    const float4* vb4 = (const float4*)p.v_b;
    const float4* db4 = (const float4*)p.deconv_b;
    const float4* ob4 = (const float4*)p.out_b;
    float4* v4 = (float4*)p.v_buf;
    float4* y4 = (float4*)p.y;
    float4* o4 = (float4*)p.dout;
#pragma unroll
    for (int s = 0; s < 16; ++s) {
      int f = s * 7680 + iv;
      if (f < 24576) {
        v4[f] = vb4[f % 96];
      } else if (f < 73728) {
        int j = f - 24576;
        y4[j] = db4[j % 192];
      } else {
        int j = f - 73728;
        o4[j] = ob4[j % 192];
      }
    }
  }
}

// ======== Stage 2: v-gemm (splitk4, atomic) | A-dots | Bk-dots ========
__global__ __launch_bounds__(256) void s2(P p) {
  __shared__ float smem[2 * 32 * ASS + 2 * 32 * BSS];  // 6528 floats
  const int bid = blockIdx.x, tid = threadIdx.x;
  if (bid < 192) {
    int kz = bid & 3, t = bid >> 2;  // t 0..47
    gemm_v2<4, true>(p.nq0, p.nq1, p.nq2, p.nq3, p.conv_b, p.v_w, nullptr,
                     p.v_buf, 384, (t / 6) * 32, (t % 6) * 64, kz * 192, 6, smem);
    return;
  }
  int wave = (bid - 192) * 4 + (tid >> 6);  // 0..1535
  int lane = tid & 63;
  for (int W = wave; W < 6144; W += 1536) {
    if (W < 1536) {  // A q-part
      int x = W & 127, q = W >> 7;
      int b = q / 6, h = q % 6;
      const size_t row = (size_t)(x * 2 + b) * 768;
      const float* ww = p.qw_red + h * 768;
      float pacc = 0.f;
#pragma unroll
      for (int it = 0; it < 12; ++it) {
        int i = it * 64 + lane;
        float nv = p.nq0[row + i] + p.nq1[row + i] + p.nq2[row + i] +
                   p.nq3[row + i] + p.conv_b[i];
        pacc += nv * ww[i];
      }
      float s = wsum(pacc) + p.qb_red[h];
      if (lane == 0) p.Abuf[(b * 12 + h) * 128 + x] = s;
    } else if (W < 3072) {  // A e-part
      int r = W - 1536;
      int x = r & 127, q = r >> 7;
      int b = q / 6, he = q % 6;
      float s = wsum(p.e_buf[(size_t)(x * 2 + b) * 384 + he * 64 + lane] * p.attn_w[lane]);
      if (lane == 0) p.Abuf[(b * 12 + 6 + he) * 128 + x] = s;
    } else if (W < 4608) {  // Bk q-part
      int r = W - 3072;
      int l = r & 127, q = r >> 7;
      int b = q / 6, h = q % 6;
      const size_t row = (size_t)(l * 2 + b) * 768;
      const float* ww = p.kw_red + h * 768;
      float pacc = 0.f;
#pragma unroll
      for (int it = 0; it < 12; ++it) {
        int i = it * 64 + lane;
        float nv = p.nq0[row + i] + p.nq1[row + i] + p.nq2[row + i] +
                   p.nq3[row + i] + p.conv_b[i];
        pacc += nv * ww[i];
      }
      float s = wsum(pacc) + p.kb_red[h];
      if (lane == 0) p.Bkbuf[(b * 12 + h) * 128 + l] = s;
    } else {  // Bk e-part
      int r = W - 4608;
      int l = r & 127, q = r >> 7;
      int b = q / 6, he = q % 6;
      float s = wsum(p.e_buf[(size_t)(l * 2 + b) * 384 + he * 64 + lane] * p.attn_w[64 + lane]);
      if (lane == 0) p.Bkbuf[(b * 12 + 6 + he) * 128 + l] = s;
    }
  }
}

// ======== Stage 3: scores + leaky_relu + softmax + PV (2 units / 256-thr block) ====
__global__ __launch_bounds__(256) void s3(P p) {
  __shared__ float smem[520];
  float* ps   = smem;        // [2][128]
  float* redm = smem + 256;  // [2][2]
  float* reds = smem + 260;  // [2][2]
  float* pv   = smem + 264;  // [2][128]
  const int tid = threadIdx.x;
  const int half = tid >> 7;
  const int t = tid & 127;
  const int widx = (tid >> 6) & 1;
  const int lane = tid & 63;
  const float ab0 = p.attn_b[0];

  int u = blockIdx.x * 2 + half;  // (bh,i2) unit, 0..3071
  int bh = u >> 7, i2 = u & 127;
  int j = t;
  int G = u * 128 + j;
  int mq = G % 24, xq = (G / 24) >> 7;
  int mk = u % 24;
  int cb = G % 12, gb = G / 12;
  int be = gb & 1, ij = gb >> 1, ie = ij >> 7, je = ij & 127;
  float s = p.Abuf[mq * 128 + xq] + p.Bkbuf[mk * 128 + j] +
            p.Ewbuf[ie * 24 + be * 12 + cb] - p.Ewbuf[je * 24 + be * 12 + cb] + ab0;
  s = s >= 0.f ? s : 0.01f * s;

  float mv = s;
#pragma unroll
  for (int off = 32; off; off >>= 1) mv = fmaxf(mv, __shfl_xor(mv, off, 64));
  if (lane == 0) redm[half * 2 + widx] = mv;
  __syncthreads();
  float gmax = fmaxf(redm[half * 2], redm[half * 2 + 1]);
  float ex = expf(s - gmax);
  float sv = wsum(ex);
  if (lane == 0) reds[half * 2 + widx] = sv;
  __syncthreads();
  float gsum = reds[half * 2] + reds[half * 2 + 1];
  ps[half * 128 + t] = ex / gsum;
  __syncthreads();

  int d = t & 63, jh = t >> 6;
  int b = bh / 12, h = bh % 12;
  const float* src = (h < 6) ? (p.v_buf + h * 64) : (p.e_buf + (h - 6) * 64);
  float acc = 0.f;
#pragma unroll 8
  for (int jj = 0; jj < 64; ++jj) {
    int jx = jh * 64 + jj;
    acc += ps[half * 128 + jx] * src[(size_t)(jx * 2 + b) * 384 + d];
  }
  pv[half * 128 + jh * 64 + d] = acc;
  __syncthreads();
  if (t < 64) {
    p.a_buf[(size_t)(i2 * 2 + b) * 768 + h * 64 + t] =
        pv[half * 128 + t] + pv[half * 128 + 64 + t];
  }
}

// ======== Stage 4: deconv splitk4, atomic into pre-biased y ========
__global__ __launch_bounds__(256) void s4(P p) {
  __shared__ float smem[2 * 32 * ASS + 4 * 32 * BSS];
  int kz = blockIdx.x & 3, t = blockIdx.x >> 2;
  conv_v2<1, true>(p.a_buf, p.deconv_w, p.y, (t / 12) * 32, (t % 12) * 64,
                   kz * 192, 6, smem);
}

// ======== Stage 5: out splitk4, atomic into pre-biased d_out ========
__global__ __launch_bounds__(256) void s5(P p) {
  __shared__ float smem[2 * 32 * ASS + 2 * 32 * BSS];
  int kz = blockIdx.x & 3, t = blockIdx.x >> 2;
  gemm_v2<0, true>(p.y, nullptr, nullptr, nullptr, nullptr, p.out_w, nullptr,
                   p.dout, 768, (t / 12) * 32, (t % 12) * 64, kz * 192, 6, smem);
}

extern "C" void kernel_launch(void* const* d_in, const int* in_sizes, int n_in,
                              void* d_out, int out_size, void* d_ws, size_t ws_size,
                              hipStream_t stream) {
  P p;
  p.query    = (const float*)d_in[0];
  p.entity   = (const float*)d_in[1];
  p.conv_w   = (const float*)d_in[2];
  p.conv_b   = (const float*)d_in[3];
  p.q_w      = (const float*)d_in[4];
  p.q_b      = (const float*)d_in[5];
  p.k_w      = (const float*)d_in[6];
  p.k_b      = (const float*)d_in[7];
  p.v_w      = (const float*)d_in[8];
  p.v_b      = (const float*)d_in[9];
  p.e_w      = (const float*)d_in[10];
  p.e_b      = (const float*)d_in[11];
  p.attn_w   = (const float*)d_in[12];
  p.attn_b   = (const float*)d_in[13];
  p.deconv_w = (const float*)d_in[14];
  p.deconv_b = (const float*)d_in[15];
  p.out_w    = (const float*)d_in[16];
  p.out_b    = (const float*)d_in[17];

  float* ws = (float*)d_ws;
  p.nq0    = ws;                  // 196608 each
  p.nq1    = p.nq0 + 196608;
  p.nq2    = p.nq1 + 196608;
  p.nq3    = p.nq2 + 196608;
  p.e_buf  = p.nq3 + 196608;      // 98304
  p.v_buf  = p.e_buf + 98304;     // 98304
  p.qw_red = p.v_buf + 98304;     // 4608
  p.kw_red = p.qw_red + 4608;     // 4608
  p.qb_red = p.kw_red + 4608;     // 8
  p.kb_red = p.qb_red + 8;        // 8
  p.Abuf   = p.kb_red + 8;        // 3072
  p.Bkbuf  = p.Abuf + 3072;       // 3072
  p.Ewbuf  = p.Bkbuf + 3072;      // 3072
  p.a_buf  = p.Ewbuf + 3072;      // 196608
  p.y      = p.a_buf + 196608;    // 196608
  p.dout   = (float*)d_out;

  s1<<<566, 256, 0, stream>>>(p);
  s2<<<576, 256, 0, stream>>>(p);
  s3<<<1536, 256, 0, stream>>>(p);
  s4<<<384, 256, 0, stream>>>(p);
  s5<<<384, 256, 0, stream>>>(p);
}